// Round 4
// baseline (26.518 us; speedup 1.0000x reference)
//
#include <hip/hip_runtime.h>
#include <math.h>
#include <float.h>

// Problem constants (match reference setup_inputs)
#define BB 8
#define NN 2048
#define BN (BB * NN)
#define BLK 256
#define Q 8                     // queries per thread: 256*8 = 2048 = full batch
#define CSPLIT 64               // candidate splits per (task,batch)
#define CCHUNK (NN / CSPLIT)    // 32 candidates staged per block

// Workspace layout (every slot written every call; no init kernel needed):
//   float minpart[CSPLIT][2*BN]   @ 0          (8 MB)
//   float champart[64]            @ 8 MB
//   float l1part[64]              @ +256
//   float cntpart[64]             @ +512
//   uint  counter                 @ +768       (zeroed by k_main block 0)
#define MINPART_FLOATS (CSPLIT * 2 * BN)

__global__ __launch_bounds__(BLK) void k_main(const float* __restrict__ pred,
                                              const float* __restrict__ target,
                                              const float* __restrict__ points,
                                              const int* __restrict__ mask,
                                              float* __restrict__ minpart,
                                              float* __restrict__ l1part,
                                              float* __restrict__ cntpart,
                                              unsigned int* __restrict__ counter) {
    // bid bits: cs(6) | b(3) | task(1)  -> 1024 blocks
    int bid = blockIdx.x;
    int cs = bid & (CSPLIT - 1);
    int b = (bid >> 6) & 7;
    int task = bid >> 9;   // 0: query=clean(points+target), cand=predp(points+pred)
                           // 1: query=predp,               cand=clean
    int t = threadIdx.x;

    if (bid == 0 && t == 0) *counter = 0u;  // ticket reset for k_redfin (stream-ordered)

    const float* dq = task ? pred : target;   // query delta
    const float* dc = task ? target : pred;   // candidate delta

    __shared__ float4 cand[CCHUNK];
    if (t < CCHUNK) {
        int g = b * NN + cs * CCHUNK + t;
        size_t g3 = (size_t)g * 3;
        float x = 1e30f, y = 1e30f, z = 1e30f;  // invalid: loses every min, stays finite
        if (mask[g]) {
            x = points[g3 + 0] + dc[g3 + 0];
            y = points[g3 + 1] + dc[g3 + 1];
            z = points[g3 + 2] + dc[g3 + 2];
        }
        cand[t] = make_float4(x, y, z, 0.f);
    }
    __syncthreads();

    float qx[Q], qy[Q], qz[Q], mn[Q];
    #pragma unroll
    for (int q = 0; q < Q; ++q) {
        size_t g3 = (size_t)(b * NN + q * BLK + t) * 3;
        qx[q] = points[g3 + 0] + dq[g3 + 0];
        qy[q] = points[g3 + 1] + dq[g3 + 1];
        qz[q] = points[g3 + 2] + dq[g3 + 2];
        mn[q] = FLT_MAX;
    }

    #pragma unroll 4
    for (int j = 0; j < CCHUNK; j += 2) {
        float4 c0 = cand[j];       // broadcast ds_read_b128, conflict-free
        float4 c1 = cand[j + 1];
        #pragma unroll
        for (int q = 0; q < Q; ++q) {
            float d0 = fabsf(qx[q] - c0.x) + fabsf(qy[q] - c0.y) + fabsf(qz[q] - c0.z);
            float d1 = fabsf(qx[q] - c1.x) + fabsf(qy[q] - c1.y) + fabsf(qz[q] - c1.z);
            mn[q] = fminf(fminf(d0, d1), mn[q]);   // v_min3_f32; min is order-exact
        }
    }

    // non-atomic partial-min store: distinct slot per (cs, task, b, query)
    float* mp = minpart + (size_t)cs * (2 * BN) + (size_t)task * BN + b * NN;
    #pragma unroll
    for (int q = 0; q < Q; ++q)
        mp[q * BLK + t] = mn[q];

    // Fused masked-L1 + valid-count, spread over 64 blocks (task0, cs<8), 1 query/thread
    if (task == 0 && cs < 8) {
        int gi = b * NN + cs * BLK + t;
        size_t g3 = (size_t)gi * 3;
        float m = (float)mask[gi];
        float s = (fabsf(pred[g3 + 0] - target[g3 + 0]) +
                   fabsf(pred[g3 + 1] - target[g3 + 1]) +
                   fabsf(pred[g3 + 2] - target[g3 + 2])) * (1.0f / 3.0f) * m;
        float c = m;
        for (int off = 32; off; off >>= 1) {
            s += __shfl_down(s, off, 64);
            c += __shfl_down(c, off, 64);
        }
        __shared__ float ls[4], lc[4];
        if ((t & 63) == 0) { ls[t >> 6] = s; lc[t >> 6] = c; }
        __syncthreads();   // uniform per block (task, cs are block constants)
        if (t == 0) {
            l1part[b * 8 + cs]  = ls[0] + ls[1] + ls[2] + ls[3];
            cntpart[b * 8 + cs] = lc[0] + lc[1] + lc[2] + lc[3];
        }
    }
}

__global__ __launch_bounds__(BLK) void k_redfin(const float* __restrict__ minpart,
                                                const int* __restrict__ mask,
                                                const float* __restrict__ l1part,
                                                const float* __restrict__ cntpart,
                                                float* __restrict__ champart,
                                                unsigned int* __restrict__ counter,
                                                float* __restrict__ out) {
    // 64 blocks: task(1) | b(3) | s(2); each covers 512 queries, thread does 2
    int tb = blockIdx.x;
    int s4 = tb & 3;
    int b = (tb >> 2) & 7;
    int task = tb >> 5;
    int t = threadIdx.x;

    float v = 0.f;
    #pragma unroll
    for (int k = 0; k < 2; ++k) {
        int qi = s4 * 512 + k * BLK + t;
        size_t idx = (size_t)task * BN + b * NN + qi;
        float mn = minpart[idx];
        #pragma unroll
        for (int cs = 1; cs < CSPLIT; ++cs)
            mn = fminf(mn, minpart[(size_t)cs * (2 * BN) + idx]);
        v += mn * (float)mask[b * NN + qi];
    }
    for (int off = 32; off; off >>= 1) v += __shfl_down(v, off, 64);

    __shared__ float ls[4];
    __shared__ int isLast;
    __shared__ float ch[64];
    if ((t & 63) == 0) ls[t >> 6] = v;
    __syncthreads();
    if (t == 0) {
        float bs = ls[0] + ls[1] + ls[2] + ls[3];
        __hip_atomic_store(&champart[tb], bs, __ATOMIC_RELEASE, __HIP_MEMORY_SCOPE_AGENT);
        int ticket = __hip_atomic_fetch_add(counter, 1u, __ATOMIC_ACQ_REL, __HIP_MEMORY_SCOPE_AGENT);
        isLast = (ticket == 63);
    }
    __syncthreads();
    if (!isLast) return;

    // last block finalizes
    if (t < 64) ch[t] = __hip_atomic_load(&champart[t], __ATOMIC_ACQUIRE, __HIP_MEMORY_SCOPE_AGENT);
    __syncthreads();
    if (t == 0) {
        double cnt[BB], msum = 0.0, l1num = 0.0;
        for (int b2 = 0; b2 < BB; ++b2) {
            double cb = 0.0;
            for (int k = 0; k < 8; ++k) {
                cb += (double)cntpart[b2 * 8 + k];
                l1num += (double)l1part[b2 * 8 + k];
            }
            cnt[b2] = cb;
            msum += cb;
        }
        double l1 = l1num / msum;
        double cd = 0.0;
        for (int b2 = 0; b2 < BB; ++b2) {
            double chb = 0.0;
            for (int tk = 0; tk < 2; ++tk)
                for (int s = 0; s < 4; ++s)
                    chb += (double)ch[tk * 32 + b2 * 4 + s];
            cd += chb / cnt[b2];
        }
        cd *= (1.0 / BB);
        out[0] = (float)(l1 + exp(-l1) * cd);
    }
}

extern "C" void kernel_launch(void* const* d_in, const int* in_sizes, int n_in,
                              void* d_out, int out_size, void* d_ws, size_t ws_size,
                              hipStream_t stream) {
    const float* pred   = (const float*)d_in[0];
    const float* target = (const float*)d_in[1];
    const int*   mask   = (const int*)d_in[2];
    const float* points = (const float*)d_in[3];
    float* out = (float*)d_out;

    float* minpart  = (float*)d_ws;
    char* tail = (char*)d_ws + (size_t)MINPART_FLOATS * 4;
    float* champart = (float*)tail;
    float* l1part   = (float*)(tail + 256);
    float* cntpart  = (float*)(tail + 512);
    unsigned int* counter = (unsigned int*)(tail + 768);

    k_main<<<2 * BB * CSPLIT, BLK, 0, stream>>>(pred, target, points, mask,
                                                minpart, l1part, cntpart, counter);
    k_redfin<<<64, BLK, 0, stream>>>(minpart, mask, l1part, cntpart,
                                     champart, counter, out);
}

// Round 5
// 23.638 us; speedup vs baseline: 1.1219x; 1.1219x over previous
//
#include <hip/hip_runtime.h>
#include <math.h>
#include <float.h>

// Problem constants (match reference setup_inputs)
#define BB 8
#define NN 2048
#define BN (BB * NN)
#define BLK 256
#define Q 2                     // queries per thread
#define QSPLIT 4                // query slices per (task,b): 4 * 512 = 2048
#define QSLICE (BLK * Q)        // 512 queries per block
#define CSPLIT 16               // candidate splits per (task,batch)
#define CCHUNK (NN / CSPLIT)    // 128 candidates staged per block

// Workspace layout (every slot written every call; no init kernel needed):
//   float minpart[CSPLIT][2*BN]   @ 0          (2 MB)
//   float champart[128]           @ 2 MB
//   float l1part[32]              @ +512
//   float cntpart[32]             @ +640
//   uint  counter                 @ +768       (zeroed by k_main block 0)
#define MINPART_FLOATS (CSPLIT * 2 * BN)

__global__ __launch_bounds__(BLK) void k_main(const float* __restrict__ pred,
                                              const float* __restrict__ target,
                                              const float* __restrict__ points,
                                              const int* __restrict__ mask,
                                              float* __restrict__ minpart,
                                              float* __restrict__ l1part,
                                              float* __restrict__ cntpart,
                                              unsigned int* __restrict__ counter) {
    // bid bits: cs(4) | qs(2) | b(3) | task(1)  -> 1024 blocks
    int bid = blockIdx.x;
    int cs = bid & (CSPLIT - 1);
    int qs = (bid >> 4) & (QSPLIT - 1);
    int b = (bid >> 6) & 7;
    int task = bid >> 9;   // 0: query=clean(points+target), cand=predp(points+pred)
                           // 1: query=predp,               cand=clean
    int t = threadIdx.x;

    if (bid == 0 && t == 0) *counter = 0u;  // ticket reset for k_redfin (stream-ordered)

    const float* dq = task ? pred : target;   // query delta
    const float* dc = task ? target : pred;   // candidate delta

    __shared__ float4 cand[CCHUNK];
    if (t < CCHUNK) {
        int g = b * NN + cs * CCHUNK + t;
        size_t g3 = (size_t)g * 3;
        float x = 1e30f, y = 1e30f, z = 1e30f;  // invalid: loses every min, stays finite
        if (mask[g]) {
            x = points[g3 + 0] + dc[g3 + 0];
            y = points[g3 + 1] + dc[g3 + 1];
            z = points[g3 + 2] + dc[g3 + 2];
        }
        cand[t] = make_float4(x, y, z, 0.f);
    }
    __syncthreads();

    float qx[Q], qy[Q], qz[Q], mn[Q];
    #pragma unroll
    for (int q = 0; q < Q; ++q) {
        int qi = qs * QSLICE + q * BLK + t;
        size_t g3 = (size_t)(b * NN + qi) * 3;
        qx[q] = points[g3 + 0] + dq[g3 + 0];
        qy[q] = points[g3 + 1] + dq[g3 + 1];
        qz[q] = points[g3 + 2] + dq[g3 + 2];
        mn[q] = FLT_MAX;
    }

    #pragma unroll 8
    for (int j = 0; j < CCHUNK; j += 2) {
        float4 c0 = cand[j];       // broadcast ds_read_b128, conflict-free
        float4 c1 = cand[j + 1];
        #pragma unroll
        for (int q = 0; q < Q; ++q) {
            float d0 = fabsf(qx[q] - c0.x) + fabsf(qy[q] - c0.y) + fabsf(qz[q] - c0.z);
            float d1 = fabsf(qx[q] - c1.x) + fabsf(qy[q] - c1.y) + fabsf(qz[q] - c1.z);
            mn[q] = fminf(fminf(d0, d1), mn[q]);   // v_min3_f32; min is order-exact
        }
    }

    // non-atomic partial-min store: distinct slot per (cs, task, b, query)
    float* mp = minpart + (size_t)cs * (2 * BN) + (size_t)task * BN + b * NN;
    #pragma unroll
    for (int q = 0; q < Q; ++q)
        mp[qs * QSLICE + q * BLK + t] = mn[q];

    // Fused masked-L1 + valid-count: task0/cs0 blocks (one per (b,qs)), 2 pts/thread
    if (task == 0 && cs == 0) {
        float s = 0.f, c = 0.f;
        #pragma unroll
        for (int q = 0; q < Q; ++q) {
            int gi = b * NN + qs * QSLICE + q * BLK + t;
            size_t g3 = (size_t)gi * 3;
            float m = (float)mask[gi];
            s += (fabsf(pred[g3 + 0] - target[g3 + 0]) +
                  fabsf(pred[g3 + 1] - target[g3 + 1]) +
                  fabsf(pred[g3 + 2] - target[g3 + 2])) * (1.0f / 3.0f) * m;
            c += m;
        }
        for (int off = 32; off; off >>= 1) {
            s += __shfl_down(s, off, 64);
            c += __shfl_down(c, off, 64);
        }
        __shared__ float ls[4], lc[4];
        if ((t & 63) == 0) { ls[t >> 6] = s; lc[t >> 6] = c; }
        __syncthreads();   // uniform per block (task, cs are block constants)
        if (t == 0) {
            l1part[b * QSPLIT + qs]  = ls[0] + ls[1] + ls[2] + ls[3];
            cntpart[b * QSPLIT + qs] = lc[0] + lc[1] + lc[2] + lc[3];
        }
    }
}

__global__ __launch_bounds__(BLK) void k_redfin(const float* __restrict__ minpart,
                                                const int* __restrict__ mask,
                                                const float* __restrict__ l1part,
                                                const float* __restrict__ cntpart,
                                                float* __restrict__ champart,
                                                unsigned int* __restrict__ counter,
                                                float* __restrict__ out) {
    // 128 blocks: task(1) | b(3) | s(3); each covers 256 queries, 1 per thread
    int tb = blockIdx.x;
    int s8 = tb & 7;
    int b = (tb >> 3) & 7;
    int task = tb >> 6;
    int t = threadIdx.x;

    int qi = s8 * BLK + t;
    size_t idx = (size_t)task * BN + b * NN + qi;
    float mn = minpart[idx];
    #pragma unroll
    for (int cs = 1; cs < CSPLIT; ++cs)
        mn = fminf(mn, minpart[(size_t)cs * (2 * BN) + idx]);
    float v = mn * (float)mask[b * NN + qi];

    for (int off = 32; off; off >>= 1) v += __shfl_down(v, off, 64);

    __shared__ float ls[4];
    __shared__ int isLast;
    __shared__ float ch[128];
    if ((t & 63) == 0) ls[t >> 6] = v;
    __syncthreads();
    if (t == 0) {
        float bs = ls[0] + ls[1] + ls[2] + ls[3];
        __hip_atomic_store(&champart[tb], bs, __ATOMIC_RELEASE, __HIP_MEMORY_SCOPE_AGENT);
        int ticket = __hip_atomic_fetch_add(counter, 1u, __ATOMIC_ACQ_REL, __HIP_MEMORY_SCOPE_AGENT);
        isLast = (ticket == 127);
    }
    __syncthreads();
    if (!isLast) return;

    // last block finalizes
    if (t < 128) ch[t] = __hip_atomic_load(&champart[t], __ATOMIC_ACQUIRE, __HIP_MEMORY_SCOPE_AGENT);
    __syncthreads();
    if (t == 0) {
        double cnt[BB], msum = 0.0, l1num = 0.0;
        for (int b2 = 0; b2 < BB; ++b2) {
            double cb = 0.0;
            for (int k = 0; k < QSPLIT; ++k) {
                cb += (double)cntpart[b2 * QSPLIT + k];
                l1num += (double)l1part[b2 * QSPLIT + k];
            }
            cnt[b2] = cb;
            msum += cb;
        }
        double l1 = l1num / msum;
        double cd = 0.0;
        for (int b2 = 0; b2 < BB; ++b2) {
            double chb = 0.0;
            for (int tk = 0; tk < 2; ++tk)
                for (int s = 0; s < 8; ++s)
                    chb += (double)ch[tk * 64 + b2 * 8 + s];
            cd += chb / cnt[b2];
        }
        cd *= (1.0 / BB);
        out[0] = (float)(l1 + exp(-l1) * cd);
    }
}

extern "C" void kernel_launch(void* const* d_in, const int* in_sizes, int n_in,
                              void* d_out, int out_size, void* d_ws, size_t ws_size,
                              hipStream_t stream) {
    const float* pred   = (const float*)d_in[0];
    const float* target = (const float*)d_in[1];
    const int*   mask   = (const int*)d_in[2];
    const float* points = (const float*)d_in[3];
    float* out = (float*)d_out;

    float* minpart  = (float*)d_ws;
    char* tail = (char*)d_ws + (size_t)MINPART_FLOATS * 4;
    float* champart = (float*)tail;
    float* l1part   = (float*)(tail + 512);
    float* cntpart  = (float*)(tail + 640);
    unsigned int* counter = (unsigned int*)(tail + 768);

    k_main<<<2 * BB * QSPLIT * CSPLIT, BLK, 0, stream>>>(pred, target, points, mask,
                                                         minpart, l1part, cntpart, counter);
    k_redfin<<<128, BLK, 0, stream>>>(minpart, mask, l1part, cntpart,
                                      champart, counter, out);
}